// Round 1
// baseline (199.896 us; speedup 1.0000x reference)
//
#include <hip/hip_runtime.h>
#include <math.h>

// Problem constants (fixed by setup_inputs): B=32, S=64, H=256.
#define EPSF 1e-8f
constexpr int B = 32;
constexpr int S = 64;
constexpr int H = 256;                 // floats per cell
constexpr int H4 = H / 4;              // float4 per cell = 64 (one per lane)
constexpr int CELLS_PER_BATCH = S * S; // 4096
constexpr int CELLS = B * CELLS_PER_BATCH; // 131072
constexpr int CELLS_PER_WAVE = 8;
constexpr int WAVES_PER_BLOCK = 4;     // 256 threads
constexpr int CELLS_PER_BLOCK = CELLS_PER_WAVE * WAVES_PER_BLOCK; // 32

// ws layout (floats):
//   [0..31]                : inv_qnorm[b] = 1/(||pos_query[b]|| + eps)
//   [64 + b*32]            : epos[b]   (cacheline-spread: 128 B stride)
//   [64 + b*32 + 16]       : eneg[b]   (separate 64 B line from epos[b])
#define WS_ACC_BASE 64
#define WS_ACC_STRIDE 32
#define WS_NEG_OFF 16

// ---------------- kernel 1: q-norms + zero accumulators ----------------
__global__ __launch_bounds__(64) void prep_kernel(const float* __restrict__ pq,
                                                  float* __restrict__ ws) {
    int b = blockIdx.x;          // 0..31
    int lane = threadIdx.x;      // 0..63
    float4 v = ((const float4*)pq)[b * H4 + lane];
    float ss = v.x * v.x + v.y * v.y + v.z * v.z + v.w * v.w;
    #pragma unroll
    for (int off = 32; off > 0; off >>= 1) ss += __shfl_xor(ss, off);
    if (lane == 0) {
        ws[b] = 1.0f / (sqrtf(ss) + EPSF);
        ws[WS_ACC_BASE + b * WS_ACC_STRIDE] = 0.0f;
        ws[WS_ACC_BASE + b * WS_ACC_STRIDE + WS_NEG_OFF] = 0.0f;
    }
}

// ---------------- kernel 2: main pass over all (b,i,j) cells ----------------
__global__ __launch_bounds__(256) void main_kernel(const float* __restrict__ tmap,
                                                   const float* __restrict__ pq,
                                                   const int* __restrict__ mask_pos,
                                                   const int* __restrict__ mask_neg,
                                                   float* __restrict__ ws) {
    int tid = threadIdx.x;
    int lane = tid & 63;
    int wid = tid >> 6;
    int cellBase = blockIdx.x * CELLS_PER_BLOCK + wid * CELLS_PER_WAVE;
    int b = cellBase >> 12;  // / CELLS_PER_BATCH; block never straddles a batch

    // wave-invariant: this batch's normalized-query fragment + scale
    float4 q4 = ((const float4*)pq)[b * H4 + lane];
    float scale = ws[b] * (1.0f / (1.0f + EPSF));  // second-normalize eps factor

    float wp = 0.0f, wn = 0.0f;
    #pragma unroll
    for (int k = 0; k < CELLS_PER_WAVE; ++k) {
        int cell = cellBase + k;
        float4 t = ((const float4*)tmap)[cell * H4 + lane];
        float d  = t.x * q4.x + t.y * q4.y + t.z * q4.z + t.w * q4.w;
        float ss = t.x * t.x + t.y * t.y + t.z * t.z + t.w * t.w;
        #pragma unroll
        for (int off = 32; off > 0; off >>= 1) {
            d  += __shfl_xor(d, off);
            ss += __shfl_xor(ss, off);
        }
        // s = dot(t,q)/(||t||*(1+eps)) * inv_qnorm  (all lanes hold same value)
        float s = d * scale * rsqrtf(ss);
        float e = __expf(s);  // TAO = 1
        if (mask_pos[cell] != 0) wp += e;
        if (mask_neg[cell] != 0) wn += e;
    }

    __shared__ float sp[WAVES_PER_BLOCK], sn[WAVES_PER_BLOCK];
    if (lane == 0) { sp[wid] = wp; sn[wid] = wn; }
    __syncthreads();
    if (tid == 0) {
        float tp = 0.0f, tn = 0.0f;
        #pragma unroll
        for (int w = 0; w < WAVES_PER_BLOCK; ++w) { tp += sp[w]; tn += sn[w]; }
        atomicAdd(&ws[WS_ACC_BASE + b * WS_ACC_STRIDE], tp);
        atomicAdd(&ws[WS_ACC_BASE + b * WS_ACC_STRIDE + WS_NEG_OFF], tn);
    }
}

// ---------------- kernel 3: per-batch loss + average ----------------
__global__ __launch_bounds__(64) void final_kernel(const float* __restrict__ ws,
                                                   float* __restrict__ out) {
    int lane = threadIdx.x;  // 0..63
    float li = 0.0f;
    int v = 0;
    if (lane < B) {
        float ep = ws[WS_ACC_BASE + lane * WS_ACC_STRIDE];
        float en = ws[WS_ACC_BASE + lane * WS_ACC_STRIDE + WS_NEG_OFF];
        if (ep > 0.0f && en > 0.0f) {  // == any(mask_pos) && any(mask_neg), since exp>0
            v = 1;
            li = -logf(ep / (ep + en + EPSF));
        }
    }
    #pragma unroll
    for (int off = 32; off > 0; off >>= 1) {
        li += __shfl_xor(li, off);
        v  += __shfl_xor(v, off);
    }
    if (lane == 0) out[0] = li / (float)(v > 0 ? v : 1);
}

extern "C" void kernel_launch(void* const* d_in, const int* in_sizes, int n_in,
                              void* d_out, int out_size, void* d_ws, size_t ws_size,
                              hipStream_t stream) {
    const float* pos_query = (const float*)d_in[0];  // (B,H) fp32
    const float* tmap      = (const float*)d_in[1];  // (B,S,S,H) fp32
    const int*   mask_pos  = (const int*)d_in[2];    // (B,S,S) bool -> int32
    const int*   mask_neg  = (const int*)d_in[3];
    float* out = (float*)d_out;
    float* ws  = (float*)d_ws;

    prep_kernel<<<B, 64, 0, stream>>>(pos_query, ws);
    main_kernel<<<CELLS / CELLS_PER_BLOCK, 256, 0, stream>>>(tmap, pos_query,
                                                             mask_pos, mask_neg, ws);
    final_kernel<<<1, 64, 0, stream>>>(ws, out);
}